// Round 1
// baseline (1702.990 us; speedup 1.0000x reference)
//
#include <hip/hip_runtime.h>

#define DIM 64

// ---------------- prep kernels ----------------

__global__ void zero_ints(int* __restrict__ p, int n) {
    int i = blockIdx.x * blockDim.x + threadIdx.x;
    if (i < n) p[i] = 0;
}

// count in-degree: cnt[col[e]]++
__global__ void hist_kernel(const int* __restrict__ edge, int E, int* __restrict__ cnt) {
    int i = blockIdx.x * blockDim.x + threadIdx.x;
    if (i < E) {
        int c = edge[E + i];          // edge_index[1][i]
        atomicAdd(&cnt[c], 1);
    }
}

// single-block exclusive scan over n counts -> offsets[0..n], cursor copy
__global__ __launch_bounds__(1024) void scan_kernel(const int* __restrict__ cnt,
                                                    int* __restrict__ offsets,
                                                    int* __restrict__ cursor,
                                                    int n) {
    __shared__ int lds[1024];
    const int T = 1024, K = 4, CHUNK = T * K;
    int carry = 0;
    for (int base = 0; base < n; base += CHUNK) {
        int v[K];
        int idx0 = base + (int)threadIdx.x * K;
#pragma unroll
        for (int k = 0; k < K; ++k) {
            int i = idx0 + k;
            v[k] = (i < n) ? cnt[i] : 0;
        }
        int tsum = v[0] + v[1] + v[2] + v[3];
        lds[threadIdx.x] = tsum;
        __syncthreads();
        int incl = tsum;
        for (int off = 1; off < T; off <<= 1) {
            int t = (threadIdx.x >= (unsigned)off) ? lds[threadIdx.x - off] : 0;
            __syncthreads();
            incl += t;
            lds[threadIdx.x] = incl;
            __syncthreads();
        }
        int total = lds[T - 1];
        int run = carry + (incl - tsum);
#pragma unroll
        for (int k = 0; k < K; ++k) {
            int i = idx0 + k;
            if (i < n) { offsets[i] = run; cursor[i] = run; }
            run += v[k];
        }
        carry += total;
        __syncthreads();
    }
    if (threadIdx.x == 0) offsets[n] = carry;
}

__global__ void dinv_kernel(const int* __restrict__ cnt, float* __restrict__ dinv, int n) {
    int i = blockIdx.x * blockDim.x + threadIdx.x;
    if (i < n) {
        int d = cnt[i];
        dinv[i] = (d > 0) ? rsqrtf((float)d) : 0.0f;
    }
}

// scatter edges into CSR (sorted by target node)
__global__ void scatter_kernel(const int* __restrict__ edge, int E,
                               int* __restrict__ cursor,
                               int* __restrict__ row_sorted) {
    int i = blockIdx.x * blockDim.x + threadIdx.x;
    if (i < E) {
        int r = edge[i];              // source
        int c = edge[E + i];          // target
        int p = atomicAdd(&cursor[c], 1);
        row_sorted[p] = r;
    }
}

// out = 0.25*x0 ; y0 = dinv * x0
__global__ void init_kernel(const float* __restrict__ user,
                            const float* __restrict__ item,
                            const float* __restrict__ dinv,
                            float* __restrict__ out,
                            float* __restrict__ y,
                            int nU, int total) {
    int i = blockIdx.x * blockDim.x + threadIdx.x;
    if (i < total) {
        int node = i >> 6;
        float v = (node < nU) ? user[i] : item[i - nU * DIM];
        out[i] = 0.25f * v;
        y[i] = dinv[node] * v;
    }
}

// one wave (64 lanes) per node, lane = dim
template<bool LAST>
__global__ __launch_bounds__(256) void layer_kernel(const int* __restrict__ offsets,
                                                    const int* __restrict__ row_sorted,
                                                    const float* __restrict__ dinv,
                                                    const float* __restrict__ y_in,
                                                    float* __restrict__ y_out,
                                                    float* __restrict__ out,
                                                    int nN) {
    int wave = (int)((blockIdx.x * blockDim.x + threadIdx.x) >> 6);
    int lane = threadIdx.x & 63;
    if (wave >= nN) return;
    int beg = offsets[wave];
    int end = offsets[wave + 1];
    float s = 0.0f;
    for (int i = beg; i < end; ++i) {
        int r = row_sorted[i];
        s += y_in[(size_t)r * DIM + lane];
    }
    float dc = dinv[wave];
    float xn = dc * s;
    size_t o = (size_t)wave * DIM + lane;
    out[o] += 0.25f * xn;
    if (!LAST) y_out[o] = dc * xn;
}

// ---------------- host launcher ----------------

extern "C" void kernel_launch(void* const* d_in, const int* in_sizes, int n_in,
                              void* d_out, int out_size, void* d_ws, size_t ws_size,
                              hipStream_t stream) {
    const float* user = (const float*)d_in[0];
    const float* item = (const float*)d_in[1];
    const int*   edge = (const int*)d_in[2];

    const int nU = in_sizes[0] / DIM;
    const int nI = in_sizes[1] / DIM;
    const int nN = nU + nI;
    const int E  = in_sizes[2] / 2;
    const int total = nN * DIM;

    float* out = (float*)d_out;

    // workspace carve-up (256B aligned)
    char* ws = (char*)d_ws;
    size_t off = 0;
    auto take = [&](size_t bytes) -> char* {
        char* p = ws + off;
        off = (off + bytes + 255) & ~(size_t)255;
        return p;
    };
    int*   cnt        = (int*)  take((size_t)nN * 4);
    int*   offsets    = (int*)  take((size_t)(nN + 1) * 4);
    int*   cursor     = (int*)  take((size_t)nN * 4);
    float* dinv       = (float*)take((size_t)nN * 4);
    int*   row_sorted = (int*)  take((size_t)E * 4);
    float* y0         = (float*)take((size_t)total * 4);
    float* y1         = (float*)take((size_t)total * 4);
    (void)ws_size; (void)n_in; (void)out_size;

    const int B = 256;
    dim3 blk(B);

    // 1. zero counts
    zero_ints<<<dim3((nN + B - 1) / B), blk, 0, stream>>>(cnt, nN);
    // 2. degree histogram
    hist_kernel<<<dim3((E + B - 1) / B), blk, 0, stream>>>(edge, E, cnt);
    // 3. exclusive scan -> offsets, cursor
    scan_kernel<<<dim3(1), dim3(1024), 0, stream>>>(cnt, offsets, cursor, nN);
    // 4. dinv
    dinv_kernel<<<dim3((nN + B - 1) / B), blk, 0, stream>>>(cnt, dinv, nN);
    // 5. scatter edges into CSR
    scatter_kernel<<<dim3((E + B - 1) / B), blk, 0, stream>>>(edge, E, cursor, row_sorted);
    // 6. init out + y0
    init_kernel<<<dim3((total + B - 1) / B), blk, 0, stream>>>(user, item, dinv, out, y0, nU, total);

    // 7. three propagation layers (wave per node)
    dim3 lgrid((nN + 3) / 4);   // 4 waves (nodes) per 256-thread block
    layer_kernel<false><<<lgrid, blk, 0, stream>>>(offsets, row_sorted, dinv, y0, y1, out, nN);
    layer_kernel<false><<<lgrid, blk, 0, stream>>>(offsets, row_sorted, dinv, y1, y0, out, nN);
    layer_kernel<true ><<<lgrid, blk, 0, stream>>>(offsets, row_sorted, dinv, y0, nullptr, out, nN);
}

// Round 2
// 1514.353 us; speedup vs baseline: 1.1246x; 1.1246x over previous
//
#include <hip/hip_runtime.h>
#include <hip/hip_fp16.h>

#define DIM 64

// ---------------- prep kernels ----------------

__global__ void zero_ints(int* __restrict__ p, int n) {
    int i = blockIdx.x * blockDim.x + threadIdx.x;
    if (i < n) p[i] = 0;
}

// count edges per coarse bucket (64 nodes / bucket)
__global__ void bucket_count_kernel(const int* __restrict__ edge, int E,
                                    int* __restrict__ bcnt) {
    int i = blockIdx.x * blockDim.x + threadIdx.x;
    if (i < E) {
        int c = edge[E + i];          // target
        atomicAdd(&bcnt[c >> 6], 1);
    }
}

// single-block exclusive scan over n counts -> offsets[0..n], cursor copy
__global__ __launch_bounds__(1024) void scan_kernel(const int* __restrict__ cnt,
                                                    int* __restrict__ offsets,
                                                    int* __restrict__ cursor,
                                                    int n) {
    __shared__ int lds[1024];
    const int T = 1024, K = 4, CHUNK = T * K;
    int carry = 0;
    for (int base = 0; base < n; base += CHUNK) {
        int v[K];
        int idx0 = base + (int)threadIdx.x * K;
#pragma unroll
        for (int k = 0; k < K; ++k) {
            int i = idx0 + k;
            v[k] = (i < n) ? cnt[i] : 0;
        }
        int tsum = v[0] + v[1] + v[2] + v[3];
        lds[threadIdx.x] = tsum;
        __syncthreads();
        int incl = tsum;
        for (int off = 1; off < T; off <<= 1) {
            int t = (threadIdx.x >= (unsigned)off) ? lds[threadIdx.x - off] : 0;
            __syncthreads();
            incl += t;
            lds[threadIdx.x] = incl;
            __syncthreads();
        }
        int total = lds[T - 1];
        int run = carry + (incl - tsum);
#pragma unroll
        for (int k = 0; k < K; ++k) {
            int i = idx0 + k;
            if (i < n) { offsets[i] = run; cursor[i] = run; }
            run += v[k];
        }
        carry += total;
        __syncthreads();
    }
    if (threadIdx.x == 0) offsets[n] = carry;
}

// bin edges by coarse bucket; entry = (row << 6) | (col & 63), 24 bits
__global__ void bin_kernel(const int* __restrict__ edge, int E,
                           int* __restrict__ bcur,
                           unsigned* __restrict__ bin) {
    int i = blockIdx.x * blockDim.x + threadIdx.x;
    if (i < E) {
        int r = edge[i];              // source
        int c = edge[E + i];          // target
        int p = atomicAdd(&bcur[c >> 6], 1);
        bin[p] = ((unsigned)r << 6) | (unsigned)(c & 63);
    }
}

// per-bucket counting sort -> CSR; also emits per-node offsets and dinv
__global__ __launch_bounds__(256) void csr_kernel(const unsigned* __restrict__ bin,
                                                  const int* __restrict__ boff,
                                                  int* __restrict__ offsets,
                                                  float* __restrict__ dinv,
                                                  int* __restrict__ row_sorted,
                                                  int nN) {
    __shared__ int lcnt[65];
    __shared__ int lcur[64];
    int b = blockIdx.x;
    int beg = boff[b], end = boff[b + 1];
    if (threadIdx.x < 64) lcnt[threadIdx.x] = 0;
    __syncthreads();
    for (int i = beg + (int)threadIdx.x; i < end; i += 256) {
        unsigned e = bin[i];
        atomicAdd(&lcnt[e & 63u], 1);
    }
    __syncthreads();
    if (threadIdx.x == 0) {
        int run = 0;
#pragma unroll
        for (int c = 0; c < 64; ++c) {
            int t = lcnt[c];
            lcnt[c] = run;            // becomes exclusive offset
            lcur[c] = 0;
            run += t;
        }
        lcnt[64] = run;
    }
    __syncthreads();
    if (threadIdx.x < 64) {
        int node = b * 64 + (int)threadIdx.x;
        if (node < nN) {
            int c0 = lcnt[threadIdx.x];
            int c1 = lcnt[threadIdx.x + 1];
            offsets[node] = beg + c0;
            int d = c1 - c0;
            dinv[node] = (d > 0) ? rsqrtf((float)d) : 0.0f;
            if (node == nN - 1) offsets[nN] = beg + c1;
        }
    }
    __syncthreads();
    for (int i = beg + (int)threadIdx.x; i < end; i += 256) {
        unsigned e = bin[i];
        int c = (int)(e & 63u);
        int p = atomicAdd(&lcur[c], 1);
        row_sorted[beg + lcnt[c] + p] = (int)(e >> 6);
    }
}

// out = 0.25*x0 ; y0 = half(dinv * x0)
__global__ void init_kernel(const float* __restrict__ user,
                            const float* __restrict__ item,
                            const float* __restrict__ dinv,
                            float* __restrict__ out,
                            __half* __restrict__ y,
                            int nU, int total) {
    int i = blockIdx.x * blockDim.x + threadIdx.x;
    if (i < total) {
        int node = i >> 6;
        float v = (node < nU) ? user[i] : item[i - nU * DIM];
        out[i] = 0.25f * v;
        y[i] = __float2half(dinv[node] * v);
    }
}

// one wave (64 lanes) per node; two edges per step (one per half-wave),
// each half-wave loads a 128B fp16 row as half2
template<bool LAST>
__global__ __launch_bounds__(256) void layer_kernel(const int* __restrict__ offsets,
                                                    const int* __restrict__ row_sorted,
                                                    const float* __restrict__ dinv,
                                                    const __half* __restrict__ y_in,
                                                    __half* __restrict__ y_out,
                                                    float* __restrict__ out,
                                                    int nN) {
    int wave = (int)((blockIdx.x * blockDim.x + threadIdx.x) >> 6);
    int lane = (int)(threadIdx.x & 63);
    if (wave >= nN) return;
    int beg = offsets[wave];
    int end = offsets[wave + 1];
    int h = lane >> 5;       // half-wave id
    int sl = lane & 31;      // sub-lane
    const __half2* y2 = (const __half2*)y_in;
    float ax = 0.0f, ay = 0.0f;
    int deg = end - beg;
    int T = (deg + 1) >> 1;
#pragma unroll 4
    for (int t = 0; t < T; ++t) {
        int e = beg + 2 * t + h;
        if (e < end) {
            int r = row_sorted[e];
            float2 v = __half22float2(y2[(size_t)r * 32 + sl]);
            ax += v.x;
            ay += v.y;
        }
    }
    // combine the two half-wave partial sums
    ax += __shfl_xor(ax, 32);
    ay += __shfl_xor(ay, 32);
    float dc = dinv[wave];
    float xnx = dc * ax, xny = dc * ay;
    if (h == 0) {
        size_t o = (size_t)wave * 32 + sl;
        float2* o2 = (float2*)out;
        float2 cur = o2[o];
        cur.x += 0.25f * xnx;
        cur.y += 0.25f * xny;
        o2[o] = cur;
        if (!LAST) {
            __half2* yo = (__half2*)y_out;
            float2 yv; yv.x = dc * xnx; yv.y = dc * xny;
            yo[o] = __float22half2_rn(yv);
        }
    }
}

// ---------------- host launcher ----------------

extern "C" void kernel_launch(void* const* d_in, const int* in_sizes, int n_in,
                              void* d_out, int out_size, void* d_ws, size_t ws_size,
                              hipStream_t stream) {
    const float* user = (const float*)d_in[0];
    const float* item = (const float*)d_in[1];
    const int*   edge = (const int*)d_in[2];

    const int nU = in_sizes[0] / DIM;
    const int nI = in_sizes[1] / DIM;
    const int nN = nU + nI;
    const int E  = in_sizes[2] / 2;
    const int total = nN * DIM;
    const int NB = (nN + 63) / 64;      // coarse buckets (64 nodes each)

    float* out = (float*)d_out;

    // workspace carve-up (256B aligned)
    char* ws = (char*)d_ws;
    size_t off = 0;
    auto take = [&](size_t bytes) -> char* {
        char* p = ws + off;
        off = (off + bytes + 255) & ~(size_t)255;
        return p;
    };
    int*      bcnt       = (int*)     take((size_t)NB * 4);
    int*      boff       = (int*)     take((size_t)(NB + 1) * 4);
    int*      bcur       = (int*)     take((size_t)NB * 4);
    unsigned* bin        = (unsigned*)take((size_t)E * 4);
    int*      offsets    = (int*)     take((size_t)(nN + 1) * 4);
    float*    dinv       = (float*)   take((size_t)nN * 4);
    int*      row_sorted = (int*)     take((size_t)E * 4);
    __half*   y0         = (__half*)  take((size_t)total * 2);
    __half*   y1         = (__half*)  take((size_t)total * 2);
    (void)ws_size; (void)n_in; (void)out_size;

    const int B = 256;
    dim3 blk(B);

    // 1. zero bucket counts
    zero_ints<<<dim3((NB + B - 1) / B), blk, 0, stream>>>(bcnt, NB);
    // 2. bucket histogram (2344 hot counters)
    bucket_count_kernel<<<dim3((E + B - 1) / B), blk, 0, stream>>>(edge, E, bcnt);
    // 3. bucket scan
    scan_kernel<<<dim3(1), dim3(1024), 0, stream>>>(bcnt, boff, bcur, NB);
    // 4. bin edges by bucket (packed 24-bit entries)
    bin_kernel<<<dim3((E + B - 1) / B), blk, 0, stream>>>(edge, E, bcur, bin);
    // 5. per-bucket counting sort -> CSR + offsets + dinv
    csr_kernel<<<dim3(NB), blk, 0, stream>>>(bin, boff, offsets, dinv, row_sorted, nN);
    // 6. init out + y0 (fp16)
    init_kernel<<<dim3((total + B - 1) / B), blk, 0, stream>>>(user, item, dinv, out, y0, nU, total);

    // 7. three propagation layers (wave per node, fp16 gathers)
    dim3 lgrid((nN + 3) / 4);   // 4 waves (nodes) per 256-thread block
    layer_kernel<false><<<lgrid, blk, 0, stream>>>(offsets, row_sorted, dinv, y0, y1, out, nN);
    layer_kernel<false><<<lgrid, blk, 0, stream>>>(offsets, row_sorted, dinv, y1, y0, out, nN);
    layer_kernel<true ><<<lgrid, blk, 0, stream>>>(offsets, row_sorted, dinv, y0, nullptr, out, nN);
}

// Round 3
// 705.041 us; speedup vs baseline: 2.4154x; 2.1479x over previous
//
#include <hip/hip_runtime.h>
#include <hip/hip_fp16.h>

#define DIM 64
#define BSH 8                 // log2(nodes per bucket) = 256 nodes/bucket
#define BMASK 255u
#define NBMAX 1024            // max coarse buckets supported
#define BINC 16384            // edges staged per bin block

// ---------------- prep kernels ----------------

__global__ void zero_ints(int* __restrict__ p, int n) {
    int i = blockIdx.x * blockDim.x + threadIdx.x;
    if (i < n) p[i] = 0;
}

// per-block LDS histogram of edges per coarse bucket, flushed with one
// atomicAdd per (block,bucket)
__global__ __launch_bounds__(1024) void bucket_count_kernel(const int* __restrict__ edge, int E,
                                                            int* __restrict__ bcnt, int NB) {
    __shared__ int lcnt[NBMAX];
    for (int i = threadIdx.x; i < NB; i += 1024) lcnt[i] = 0;
    __syncthreads();
    int stride = gridDim.x * 1024;
    for (int i = blockIdx.x * 1024 + threadIdx.x; i < E; i += stride)
        atomicAdd(&lcnt[edge[E + i] >> BSH], 1);
    __syncthreads();
    for (int i = threadIdx.x; i < NB; i += 1024) {
        int v = lcnt[i];
        if (v) atomicAdd(&bcnt[i], v);
    }
}

// single-block exclusive scan over n counts -> offsets[0..n], cursor copy
__global__ __launch_bounds__(1024) void scan_kernel(const int* __restrict__ cnt,
                                                    int* __restrict__ offsets,
                                                    int* __restrict__ cursor,
                                                    int n) {
    __shared__ int lds[1024];
    const int T = 1024, K = 4, CHUNK = T * K;
    int carry = 0;
    for (int base = 0; base < n; base += CHUNK) {
        int v[K];
        int idx0 = base + (int)threadIdx.x * K;
#pragma unroll
        for (int k = 0; k < K; ++k) {
            int i = idx0 + k;
            v[k] = (i < n) ? cnt[i] : 0;
        }
        int tsum = v[0] + v[1] + v[2] + v[3];
        lds[threadIdx.x] = tsum;
        __syncthreads();
        int incl = tsum;
        for (int off = 1; off < T; off <<= 1) {
            int t = (threadIdx.x >= (unsigned)off) ? lds[threadIdx.x - off] : 0;
            __syncthreads();
            incl += t;
            lds[threadIdx.x] = incl;
            __syncthreads();
        }
        int total = lds[T - 1];
        int run = carry + (incl - tsum);
#pragma unroll
        for (int k = 0; k < K; ++k) {
            int i = idx0 + k;
            if (i < n) { offsets[i] = run; cursor[i] = run; }
            run += v[k];
        }
        carry += total;
        __syncthreads();
    }
    if (threadIdx.x == 0) offsets[n] = carry;
}

// LDS-staged scatter: sort a 16K-edge chunk by bucket in LDS, reserve one
// contiguous global range per (block,bucket), copy out per-bucket runs.
// entry = (row << 8) | (col & 255)
__global__ __launch_bounds__(1024) void bin_kernel(const int* __restrict__ edge, int E,
                                                   int* __restrict__ bcur,
                                                   unsigned* __restrict__ bin, int NB) {
    __shared__ unsigned stage[BINC];
    __shared__ int lcnt[NBMAX];
    __shared__ int lsc[NBMAX];
    __shared__ int lcur[NBMAX];
    __shared__ int gb[NBMAX];
    const int tid = (int)threadIdx.x;
    const int beg = (int)blockIdx.x * BINC;
    const int n = min(BINC, E - beg);

    lcnt[tid] = 0;
    __syncthreads();
    // phase 1: count per bucket
    for (int i = tid; i < n; i += 1024)
        atomicAdd(&lcnt[edge[E + beg + i] >> BSH], 1);
    __syncthreads();
    // inclusive scan over 1024 slots
    lsc[tid] = lcnt[tid];
    __syncthreads();
    for (int off = 1; off < 1024; off <<= 1) {
        int t = (tid >= off) ? lsc[tid - off] : 0;
        __syncthreads();
        lsc[tid] += t;
        __syncthreads();
    }
    // reserve global ranges, init local cursors
    {
        int cb = lcnt[tid];
        lcur[tid] = lsc[tid] - cb;            // exclusive base
        if (tid < NB) gb[tid] = cb ? atomicAdd(&bcur[tid], cb) : 0;
    }
    __syncthreads();
    // phase 2: rank into LDS stage (sorted by bucket)
    for (int i = tid; i < n; i += 1024) {
        int r = edge[beg + i];
        int c = edge[E + beg + i];
        int b = c >> BSH;
        int slot = atomicAdd(&lcur[b], 1);
        stage[slot] = ((unsigned)r << BSH) | ((unsigned)c & BMASK);
    }
    __syncthreads();
    // phase 3: per-bucket coalesced-ish copy out
    const int wid = tid >> 6, lane = tid & 63;
    for (int b = wid; b < NB; b += 16) {
        int cb = lcnt[b];
        if (!cb) continue;
        int lb = lsc[b] - cb;
        int g = gb[b];
        for (int l = lane; l < cb; l += 64)
            bin[g + l] = stage[lb + l];
    }
}

// per-bucket counting sort -> CSR; also emits per-node offsets and dinv
__global__ __launch_bounds__(256) void csr_kernel(const unsigned* __restrict__ bin,
                                                  const int* __restrict__ boff,
                                                  int* __restrict__ offsets,
                                                  float* __restrict__ dinv,
                                                  int* __restrict__ row_sorted,
                                                  int nN) {
    __shared__ int lcnt[256];
    __shared__ int lsc[256];
    __shared__ int lcur[256];
    const int tid = (int)threadIdx.x;
    const int b = (int)blockIdx.x;
    const int beg = boff[b], end = boff[b + 1];
    lcnt[tid] = 0;
    __syncthreads();
    for (int i = beg + tid; i < end; i += 256)
        atomicAdd(&lcnt[bin[i] & BMASK], 1);
    __syncthreads();
    lsc[tid] = lcnt[tid];
    __syncthreads();
    for (int off = 1; off < 256; off <<= 1) {
        int t = (tid >= off) ? lsc[tid - off] : 0;
        __syncthreads();
        lsc[tid] += t;
        __syncthreads();
    }
    int cb = lcnt[tid];
    int lb = lsc[tid] - cb;
    lcur[tid] = lb;
    int node = (b << BSH) + tid;
    if (node < nN) {
        offsets[node] = beg + lb;
        dinv[node] = cb ? rsqrtf((float)cb) : 0.0f;
        if (node == nN - 1) offsets[nN] = beg + lsc[tid];
    }
    __syncthreads();
    for (int i = beg + tid; i < end; i += 256) {
        unsigned e = bin[i];
        int c = (int)(e & BMASK);
        int p = atomicAdd(&lcur[c], 1);
        row_sorted[beg + p] = (int)(e >> BSH);
    }
}

// out = 0.25*x0 ; y0 = half(dinv * x0)
__global__ void init_kernel(const float* __restrict__ user,
                            const float* __restrict__ item,
                            const float* __restrict__ dinv,
                            float* __restrict__ out,
                            __half* __restrict__ y,
                            int nU, int total) {
    int i = blockIdx.x * blockDim.x + threadIdx.x;
    if (i < total) {
        int node = i >> 6;
        float v = (node < nU) ? user[i] : item[i - nU * DIM];
        out[i] = 0.25f * v;
        y[i] = __float2half(dinv[node] * v);
    }
}

// one wave (64 lanes) per node; two edges per step (one per half-wave),
// each half-wave loads a 128B fp16 row as half2
template<bool LAST>
__global__ __launch_bounds__(256) void layer_kernel(const int* __restrict__ offsets,
                                                    const int* __restrict__ row_sorted,
                                                    const float* __restrict__ dinv,
                                                    const __half* __restrict__ y_in,
                                                    __half* __restrict__ y_out,
                                                    float* __restrict__ out,
                                                    int nN) {
    int wave = (int)((blockIdx.x * blockDim.x + threadIdx.x) >> 6);
    int lane = (int)(threadIdx.x & 63);
    if (wave >= nN) return;
    int beg = offsets[wave];
    int end = offsets[wave + 1];
    int h = lane >> 5;       // half-wave id
    int sl = lane & 31;      // sub-lane
    const __half2* y2 = (const __half2*)y_in;
    float ax = 0.0f, ay = 0.0f;
    int deg = end - beg;
    int T = (deg + 1) >> 1;
#pragma unroll 4
    for (int t = 0; t < T; ++t) {
        int e = beg + 2 * t + h;
        if (e < end) {
            int r = row_sorted[e];
            float2 v = __half22float2(y2[(size_t)r * 32 + sl]);
            ax += v.x;
            ay += v.y;
        }
    }
    ax += __shfl_xor(ax, 32);
    ay += __shfl_xor(ay, 32);
    float dc = dinv[wave];
    float xnx = dc * ax, xny = dc * ay;
    if (h == 0) {
        size_t o = (size_t)wave * 32 + sl;
        float2* o2 = (float2*)out;
        float2 cur = o2[o];
        cur.x += 0.25f * xnx;
        cur.y += 0.25f * xny;
        o2[o] = cur;
        if (!LAST) {
            __half2* yo = (__half2*)y_out;
            float2 yv; yv.x = dc * xnx; yv.y = dc * xny;
            yo[o] = __float22half2_rn(yv);
        }
    }
}

// ---------------- host launcher ----------------

extern "C" void kernel_launch(void* const* d_in, const int* in_sizes, int n_in,
                              void* d_out, int out_size, void* d_ws, size_t ws_size,
                              hipStream_t stream) {
    const float* user = (const float*)d_in[0];
    const float* item = (const float*)d_in[1];
    const int*   edge = (const int*)d_in[2];

    const int nU = in_sizes[0] / DIM;
    const int nI = in_sizes[1] / DIM;
    const int nN = nU + nI;
    const int E  = in_sizes[2] / 2;
    const int total = nN * DIM;
    const int NB = (nN + 255) / 256;     // 256-node coarse buckets

    float* out = (float*)d_out;

    // workspace carve-up (256B aligned)
    char* ws = (char*)d_ws;
    size_t off = 0;
    auto take = [&](size_t bytes) -> char* {
        char* p = ws + off;
        off = (off + bytes + 255) & ~(size_t)255;
        return p;
    };
    int*      bcnt       = (int*)     take((size_t)NB * 4);
    int*      boff       = (int*)     take((size_t)(NB + 1) * 4);
    int*      bcur       = (int*)     take((size_t)NB * 4);
    unsigned* bin        = (unsigned*)take((size_t)E * 4);
    int*      offsets    = (int*)     take((size_t)(nN + 1) * 4);
    float*    dinv       = (float*)   take((size_t)nN * 4);
    int*      row_sorted = (int*)     take((size_t)E * 4);
    __half*   y0         = (__half*)  take((size_t)total * 2);
    __half*   y1         = (__half*)  take((size_t)total * 2);
    (void)ws_size; (void)n_in; (void)out_size;

    const int B = 256;
    dim3 blk(B);

    // 1. zero bucket counts
    zero_ints<<<dim3((NB + B - 1) / B), blk, 0, stream>>>(bcnt, NB);
    // 2. bucket histogram (LDS-aggregated)
    bucket_count_kernel<<<dim3(256), dim3(1024), 0, stream>>>(edge, E, bcnt, NB);
    // 3. bucket scan
    scan_kernel<<<dim3(1), dim3(1024), 0, stream>>>(bcnt, boff, bcur, NB);
    // 4. LDS-staged scatter into bucket-sorted bin
    bin_kernel<<<dim3((E + BINC - 1) / BINC), dim3(1024), 0, stream>>>(edge, E, bcur, bin, NB);
    // 5. per-bucket counting sort -> CSR + offsets + dinv
    csr_kernel<<<dim3(NB), blk, 0, stream>>>(bin, boff, offsets, dinv, row_sorted, nN);
    // 6. init out + y0 (fp16)
    init_kernel<<<dim3((total + B - 1) / B), blk, 0, stream>>>(user, item, dinv, out, y0, nU, total);

    // 7. three propagation layers (wave per node, fp16 gathers)
    dim3 lgrid((nN + 3) / 4);   // 4 waves (nodes) per 256-thread block
    layer_kernel<false><<<lgrid, blk, 0, stream>>>(offsets, row_sorted, dinv, y0, y1, out, nN);
    layer_kernel<false><<<lgrid, blk, 0, stream>>>(offsets, row_sorted, dinv, y1, y0, out, nN);
    layer_kernel<true ><<<lgrid, blk, 0, stream>>>(offsets, row_sorted, dinv, y0, nullptr, out, nN);
}

// Round 4
// 337.523 us; speedup vs baseline: 5.0456x; 2.0889x over previous
//
#include <hip/hip_runtime.h>
#include <hip/hip_fp16.h>

#define DIM 64
#define BSH 8                 // log2(nodes per bucket) = 256 nodes/bucket
#define BMASK 255u
#define NBMAX 1024            // max coarse buckets supported
#define BINC 16384            // edges staged per bin block

// ---------------- prep kernels ----------------

__global__ void zero_ints(int* __restrict__ p, int n) {
    int i = blockIdx.x * blockDim.x + threadIdx.x;
    if (i < n) p[i] = 0;
}

// per-block LDS histogram of edges per coarse bucket, flushed with one
// atomicAdd per (block,bucket)
__global__ __launch_bounds__(1024) void bucket_count_kernel(const int* __restrict__ edge, int E,
                                                            int* __restrict__ bcnt, int NB) {
    __shared__ int lcnt[NBMAX];
    for (int i = threadIdx.x; i < NB; i += 1024) lcnt[i] = 0;
    __syncthreads();
    int stride = gridDim.x * 1024;
    for (int i = blockIdx.x * 1024 + threadIdx.x; i < E; i += stride)
        atomicAdd(&lcnt[edge[E + i] >> BSH], 1);
    __syncthreads();
    for (int i = threadIdx.x; i < NB; i += 1024) {
        int v = lcnt[i];
        if (v) atomicAdd(&bcnt[i], v);
    }
}

// single-block exclusive scan over n counts -> offsets[0..n], cursor copy
__global__ __launch_bounds__(1024) void scan_kernel(const int* __restrict__ cnt,
                                                    int* __restrict__ offsets,
                                                    int* __restrict__ cursor,
                                                    int n) {
    __shared__ int lds[1024];
    const int T = 1024, K = 4, CHUNK = T * K;
    int carry = 0;
    for (int base = 0; base < n; base += CHUNK) {
        int v[K];
        int idx0 = base + (int)threadIdx.x * K;
#pragma unroll
        for (int k = 0; k < K; ++k) {
            int i = idx0 + k;
            v[k] = (i < n) ? cnt[i] : 0;
        }
        int tsum = v[0] + v[1] + v[2] + v[3];
        lds[threadIdx.x] = tsum;
        __syncthreads();
        int incl = tsum;
        for (int off = 1; off < T; off <<= 1) {
            int t = (threadIdx.x >= (unsigned)off) ? lds[threadIdx.x - off] : 0;
            __syncthreads();
            incl += t;
            lds[threadIdx.x] = incl;
            __syncthreads();
        }
        int total = lds[T - 1];
        int run = carry + (incl - tsum);
#pragma unroll
        for (int k = 0; k < K; ++k) {
            int i = idx0 + k;
            if (i < n) { offsets[i] = run; cursor[i] = run; }
            run += v[k];
        }
        carry += total;
        __syncthreads();
    }
    if (threadIdx.x == 0) offsets[n] = carry;
}

// LDS-staged scatter: sort a 16K-edge chunk by bucket in LDS, reserve one
// contiguous global range per (block,bucket), copy out per-bucket runs.
// entry = (row << 8) | (col & 255)
__global__ __launch_bounds__(1024) void bin_kernel(const int* __restrict__ edge, int E,
                                                   int* __restrict__ bcur,
                                                   unsigned* __restrict__ bin, int NB) {
    __shared__ unsigned stage[BINC];
    __shared__ int lcnt[NBMAX];
    __shared__ int lsc[NBMAX];
    __shared__ int lcur[NBMAX];
    __shared__ int gb[NBMAX];
    const int tid = (int)threadIdx.x;
    const int beg = (int)blockIdx.x * BINC;
    const int n = min(BINC, E - beg);

    lcnt[tid] = 0;
    __syncthreads();
    // phase 1: count per bucket
    for (int i = tid; i < n; i += 1024)
        atomicAdd(&lcnt[edge[E + beg + i] >> BSH], 1);
    __syncthreads();
    // inclusive scan over 1024 slots
    lsc[tid] = lcnt[tid];
    __syncthreads();
    for (int off = 1; off < 1024; off <<= 1) {
        int t = (tid >= off) ? lsc[tid - off] : 0;
        __syncthreads();
        lsc[tid] += t;
        __syncthreads();
    }
    // reserve global ranges, init local cursors
    {
        int cb = lcnt[tid];
        lcur[tid] = lsc[tid] - cb;            // exclusive base
        if (tid < NB) gb[tid] = cb ? atomicAdd(&bcur[tid], cb) : 0;
    }
    __syncthreads();
    // phase 2: rank into LDS stage (sorted by bucket)
    for (int i = tid; i < n; i += 1024) {
        int r = edge[beg + i];
        int c = edge[E + beg + i];
        int b = c >> BSH;
        int slot = atomicAdd(&lcur[b], 1);
        stage[slot] = ((unsigned)r << BSH) | ((unsigned)c & BMASK);
    }
    __syncthreads();
    // phase 3: per-bucket coalesced-ish copy out
    const int wid = tid >> 6, lane = tid & 63;
    for (int b = wid; b < NB; b += 16) {
        int cb = lcnt[b];
        if (!cb) continue;
        int lb = lsc[b] - cb;
        int g = gb[b];
        for (int l = lane; l < cb; l += 64)
            bin[g + l] = stage[lb + l];
    }
}

// per-bucket counting sort -> CSR; also emits per-node offsets and dinv
__global__ __launch_bounds__(256) void csr_kernel(const unsigned* __restrict__ bin,
                                                  const int* __restrict__ boff,
                                                  int* __restrict__ offsets,
                                                  float* __restrict__ dinv,
                                                  int* __restrict__ row_sorted,
                                                  int nN) {
    __shared__ int lcnt[256];
    __shared__ int lsc[256];
    __shared__ int lcur[256];
    const int tid = (int)threadIdx.x;
    const int b = (int)blockIdx.x;
    const int beg = boff[b], end = boff[b + 1];
    lcnt[tid] = 0;
    __syncthreads();
    for (int i = beg + tid; i < end; i += 256)
        atomicAdd(&lcnt[bin[i] & BMASK], 1);
    __syncthreads();
    lsc[tid] = lcnt[tid];
    __syncthreads();
    for (int off = 1; off < 256; off <<= 1) {
        int t = (tid >= off) ? lsc[tid - off] : 0;
        __syncthreads();
        lsc[tid] += t;
        __syncthreads();
    }
    int cb = lcnt[tid];
    int lb = lsc[tid] - cb;
    lcur[tid] = lb;
    int node = (b << BSH) + tid;
    if (node < nN) {
        offsets[node] = beg + lb;
        dinv[node] = cb ? rsqrtf((float)cb) : 0.0f;
        if (node == nN - 1) offsets[nN] = beg + lsc[tid];
    }
    __syncthreads();
    for (int i = beg + tid; i < end; i += 256) {
        unsigned e = bin[i];
        int c = (int)(e & BMASK);
        int p = atomicAdd(&lcur[c], 1);
        row_sorted[beg + p] = (int)(e >> BSH);
    }
}

// out = 0.25*x0 ; y0 = half(dinv * x0)
__global__ void init_kernel(const float* __restrict__ user,
                            const float* __restrict__ item,
                            const float* __restrict__ dinv,
                            float* __restrict__ out,
                            __half* __restrict__ y,
                            int nU, int total) {
    int i = blockIdx.x * blockDim.x + threadIdx.x;
    if (i < total) {
        int node = i >> 6;
        float v = (node < nU) ? user[i] : item[i - nU * DIM];
        out[i] = 0.25f * v;
        y[i] = __float2half(dinv[node] * v);
    }
}

// one wave per node; 8 edge-groups x 8 lanes; each lane loads float4 (8 halves)
// -> one VMEM instruction gathers 8 rows (1KB); 2x unroll = 16 edges in flight
template<bool LAST>
__global__ __launch_bounds__(256) void layer_kernel(const int* __restrict__ offsets,
                                                    const int* __restrict__ row_sorted,
                                                    const float* __restrict__ dinv,
                                                    const __half* __restrict__ y_in,
                                                    __half* __restrict__ y_out,
                                                    float* __restrict__ out,
                                                    int nN) {
    int wave = (int)((blockIdx.x * blockDim.x + threadIdx.x) >> 6);
    int lane = (int)(threadIdx.x & 63);
    if (wave >= nN) return;
    const int beg = offsets[wave];
    const int end = offsets[wave + 1];
    const int g = lane >> 3;   // edge slot 0..7
    const int q = lane & 7;    // 16B chunk of the row, 0..7
    const float4* yv = (const float4*)y_in;
    float a0 = 0, a1 = 0, a2 = 0, a3 = 0, a4 = 0, a5 = 0, a6 = 0, a7 = 0;
    const int last = end - 1;
    for (int base = beg; base < end; base += 16) {
        int e0 = base + g;
        int e1 = e0 + 8;
        int i0 = (e0 <= last) ? e0 : last;
        int i1 = (e1 <= last) ? e1 : last;
        float m0 = (e0 <= last) ? 1.0f : 0.0f;
        float m1 = (e1 <= last) ? 1.0f : 0.0f;
        int r0 = row_sorted[i0];
        int r1 = row_sorted[i1];
        float4 v0 = yv[(size_t)r0 * 8 + q];
        float4 v1 = yv[(size_t)r1 * 8 + q];
        const __half2* h0 = (const __half2*)&v0;
        const __half2* h1 = (const __half2*)&v1;
        float2 t;
        t = __half22float2(h0[0]); a0 = fmaf(m0, t.x, a0); a1 = fmaf(m0, t.y, a1);
        t = __half22float2(h0[1]); a2 = fmaf(m0, t.x, a2); a3 = fmaf(m0, t.y, a3);
        t = __half22float2(h0[2]); a4 = fmaf(m0, t.x, a4); a5 = fmaf(m0, t.y, a5);
        t = __half22float2(h0[3]); a6 = fmaf(m0, t.x, a6); a7 = fmaf(m0, t.y, a7);
        t = __half22float2(h1[0]); a0 = fmaf(m1, t.x, a0); a1 = fmaf(m1, t.y, a1);
        t = __half22float2(h1[1]); a2 = fmaf(m1, t.x, a2); a3 = fmaf(m1, t.y, a3);
        t = __half22float2(h1[2]); a4 = fmaf(m1, t.x, a4); a5 = fmaf(m1, t.y, a5);
        t = __half22float2(h1[3]); a6 = fmaf(m1, t.x, a6); a7 = fmaf(m1, t.y, a7);
    }
    // reduce across the 8 edge-groups (lane bits 3..5)
#pragma unroll
    for (int ofs = 8; ofs <= 32; ofs <<= 1) {
        a0 += __shfl_xor(a0, ofs);
        a1 += __shfl_xor(a1, ofs);
        a2 += __shfl_xor(a2, ofs);
        a3 += __shfl_xor(a3, ofs);
        a4 += __shfl_xor(a4, ofs);
        a5 += __shfl_xor(a5, ofs);
        a6 += __shfl_xor(a6, ofs);
        a7 += __shfl_xor(a7, ofs);
    }
    float dc = dinv[wave];
    if (g == 0) {
        // lane q owns dims 8q..8q+7
        float x0 = dc * a0, x1 = dc * a1, x2 = dc * a2, x3 = dc * a3;
        float x4 = dc * a4, x5 = dc * a5, x6 = dc * a6, x7 = dc * a7;
        float4* o4 = (float4*)(out + (size_t)wave * DIM + q * 8);
        float4 c0 = o4[0], c1 = o4[1];
        c0.x += 0.25f * x0; c0.y += 0.25f * x1; c0.z += 0.25f * x2; c0.w += 0.25f * x3;
        c1.x += 0.25f * x4; c1.y += 0.25f * x5; c1.z += 0.25f * x6; c1.w += 0.25f * x7;
        o4[0] = c0; o4[1] = c1;
        if (!LAST) {
            float4 pack;
            __half2* p = (__half2*)&pack;
            p[0] = __floats2half2_rn(dc * x0, dc * x1);
            p[1] = __floats2half2_rn(dc * x2, dc * x3);
            p[2] = __floats2half2_rn(dc * x4, dc * x5);
            p[3] = __floats2half2_rn(dc * x6, dc * x7);
            ((float4*)y_out)[(size_t)wave * 8 + q] = pack;
        }
    }
}

// ---------------- host launcher ----------------

extern "C" void kernel_launch(void* const* d_in, const int* in_sizes, int n_in,
                              void* d_out, int out_size, void* d_ws, size_t ws_size,
                              hipStream_t stream) {
    const float* user = (const float*)d_in[0];
    const float* item = (const float*)d_in[1];
    const int*   edge = (const int*)d_in[2];

    const int nU = in_sizes[0] / DIM;
    const int nI = in_sizes[1] / DIM;
    const int nN = nU + nI;
    const int E  = in_sizes[2] / 2;
    const int total = nN * DIM;
    const int NB = (nN + 255) / 256;     // 256-node coarse buckets

    float* out = (float*)d_out;

    // workspace carve-up (256B aligned)
    char* ws = (char*)d_ws;
    size_t off = 0;
    auto take = [&](size_t bytes) -> char* {
        char* p = ws + off;
        off = (off + bytes + 255) & ~(size_t)255;
        return p;
    };
    int*      bcnt       = (int*)     take((size_t)NB * 4);
    int*      boff       = (int*)     take((size_t)(NB + 1) * 4);
    int*      bcur       = (int*)     take((size_t)NB * 4);
    unsigned* bin        = (unsigned*)take((size_t)E * 4);
    int*      offsets    = (int*)     take((size_t)(nN + 1) * 4);
    float*    dinv       = (float*)   take((size_t)nN * 4);
    int*      row_sorted = (int*)     take((size_t)E * 4);
    __half*   y0         = (__half*)  take((size_t)total * 2);
    __half*   y1         = (__half*)  take((size_t)total * 2);
    (void)ws_size; (void)n_in; (void)out_size;

    const int B = 256;
    dim3 blk(B);

    // 1. zero bucket counts
    zero_ints<<<dim3((NB + B - 1) / B), blk, 0, stream>>>(bcnt, NB);
    // 2. bucket histogram (LDS-aggregated)
    bucket_count_kernel<<<dim3(256), dim3(1024), 0, stream>>>(edge, E, bcnt, NB);
    // 3. bucket scan
    scan_kernel<<<dim3(1), dim3(1024), 0, stream>>>(bcnt, boff, bcur, NB);
    // 4. LDS-staged scatter into bucket-sorted bin
    bin_kernel<<<dim3((E + BINC - 1) / BINC), dim3(1024), 0, stream>>>(edge, E, bcur, bin, NB);
    // 5. per-bucket counting sort -> CSR + offsets + dinv
    csr_kernel<<<dim3(NB), blk, 0, stream>>>(bin, boff, offsets, dinv, row_sorted, nN);
    // 6. init out + y0 (fp16)
    init_kernel<<<dim3((total + B - 1) / B), blk, 0, stream>>>(user, item, dinv, out, y0, nU, total);

    // 7. three propagation layers (wave per node, 8-edge-wide fp16 gathers)
    dim3 lgrid((nN + 3) / 4);   // 4 waves (nodes) per 256-thread block
    layer_kernel<false><<<lgrid, blk, 0, stream>>>(offsets, row_sorted, dinv, y0, y1, out, nN);
    layer_kernel<false><<<lgrid, blk, 0, stream>>>(offsets, row_sorted, dinv, y1, y0, out, nN);
    layer_kernel<true ><<<lgrid, blk, 0, stream>>>(offsets, row_sorted, dinv, y0, nullptr, out, nN);
}

// Round 5
// 319.195 us; speedup vs baseline: 5.3353x; 1.0574x over previous
//
#include <hip/hip_runtime.h>
#include <hip/hip_fp16.h>

#define DIM 64
#define BSH 8                 // log2(nodes per bucket) = 256 nodes/bucket
#define BMASK 255u
#define NBMAX 1024            // max coarse buckets supported
#define BINC 16384            // edges staged per bin block

// ---------------- prep kernels ----------------

__global__ void zero_ints(int* __restrict__ p, int n) {
    int i = blockIdx.x * blockDim.x + threadIdx.x;
    if (i < n) p[i] = 0;
}

// per-block LDS histogram of edges per coarse bucket, flushed with one
// atomicAdd per (block,bucket)
__global__ __launch_bounds__(1024) void bucket_count_kernel(const int* __restrict__ edge, int E,
                                                            int* __restrict__ bcnt, int NB) {
    __shared__ int lcnt[NBMAX];
    for (int i = threadIdx.x; i < NB; i += 1024) lcnt[i] = 0;
    __syncthreads();
    int stride = gridDim.x * 1024;
    for (int i = blockIdx.x * 1024 + threadIdx.x; i < E; i += stride)
        atomicAdd(&lcnt[edge[E + i] >> BSH], 1);
    __syncthreads();
    for (int i = threadIdx.x; i < NB; i += 1024) {
        int v = lcnt[i];
        if (v) atomicAdd(&bcnt[i], v);
    }
}

// single-block exclusive scan over n counts -> offsets[0..n], cursor copy
__global__ __launch_bounds__(1024) void scan_kernel(const int* __restrict__ cnt,
                                                    int* __restrict__ offsets,
                                                    int* __restrict__ cursor,
                                                    int n) {
    __shared__ int lds[1024];
    const int T = 1024, K = 4, CHUNK = T * K;
    int carry = 0;
    for (int base = 0; base < n; base += CHUNK) {
        int v[K];
        int idx0 = base + (int)threadIdx.x * K;
#pragma unroll
        for (int k = 0; k < K; ++k) {
            int i = idx0 + k;
            v[k] = (i < n) ? cnt[i] : 0;
        }
        int tsum = v[0] + v[1] + v[2] + v[3];
        lds[threadIdx.x] = tsum;
        __syncthreads();
        int incl = tsum;
        for (int off = 1; off < T; off <<= 1) {
            int t = (threadIdx.x >= (unsigned)off) ? lds[threadIdx.x - off] : 0;
            __syncthreads();
            incl += t;
            lds[threadIdx.x] = incl;
            __syncthreads();
        }
        int total = lds[T - 1];
        int run = carry + (incl - tsum);
#pragma unroll
        for (int k = 0; k < K; ++k) {
            int i = idx0 + k;
            if (i < n) { offsets[i] = run; cursor[i] = run; }
            run += v[k];
        }
        carry += total;
        __syncthreads();
    }
    if (threadIdx.x == 0) offsets[n] = carry;
}

// LDS-staged scatter: sort a 16K-edge chunk by bucket in LDS, reserve one
// contiguous global range per (block,bucket), copy out per-bucket runs.
// entry = (row << 8) | (col & 255)
__global__ __launch_bounds__(1024) void bin_kernel(const int* __restrict__ edge, int E,
                                                   int* __restrict__ bcur,
                                                   unsigned* __restrict__ bin, int NB) {
    __shared__ unsigned stage[BINC];
    __shared__ int lcnt[NBMAX];
    __shared__ int lsc[NBMAX];
    __shared__ int lcur[NBMAX];
    __shared__ int gb[NBMAX];
    const int tid = (int)threadIdx.x;
    const int beg = (int)blockIdx.x * BINC;
    const int n = min(BINC, E - beg);

    lcnt[tid] = 0;
    __syncthreads();
    // phase 1: count per bucket
    for (int i = tid; i < n; i += 1024)
        atomicAdd(&lcnt[edge[E + beg + i] >> BSH], 1);
    __syncthreads();
    // inclusive scan over 1024 slots
    lsc[tid] = lcnt[tid];
    __syncthreads();
    for (int off = 1; off < 1024; off <<= 1) {
        int t = (tid >= off) ? lsc[tid - off] : 0;
        __syncthreads();
        lsc[tid] += t;
        __syncthreads();
    }
    // reserve global ranges, init local cursors
    {
        int cb = lcnt[tid];
        lcur[tid] = lsc[tid] - cb;            // exclusive base
        if (tid < NB) gb[tid] = cb ? atomicAdd(&bcur[tid], cb) : 0;
    }
    __syncthreads();
    // phase 2: rank into LDS stage (sorted by bucket)
    for (int i = tid; i < n; i += 1024) {
        int r = edge[beg + i];
        int c = edge[E + beg + i];
        int b = c >> BSH;
        int slot = atomicAdd(&lcur[b], 1);
        stage[slot] = ((unsigned)r << BSH) | ((unsigned)c & BMASK);
    }
    __syncthreads();
    // phase 3: per-bucket coalesced-ish copy out
    const int wid = tid >> 6, lane = tid & 63;
    for (int b = wid; b < NB; b += 16) {
        int cb = lcnt[b];
        if (!cb) continue;
        int lb = lsc[b] - cb;
        int g = gb[b];
        for (int l = lane; l < cb; l += 64)
            bin[g + l] = stage[lb + l];
    }
}

// per-bucket counting sort -> CSR + offsets + dinv + rdinv, fused with
// y0 init (y0 = fp16(dinv * emb)) since the block owns 256 contiguous nodes
__global__ __launch_bounds__(256) void csr_kernel(const unsigned* __restrict__ bin,
                                                  const int* __restrict__ boff,
                                                  const float* __restrict__ user,
                                                  const float* __restrict__ item,
                                                  int nU,
                                                  int* __restrict__ offsets,
                                                  float* __restrict__ dinv,
                                                  float* __restrict__ rdinv,
                                                  int* __restrict__ row_sorted,
                                                  __half* __restrict__ y0,
                                                  int nN) {
    __shared__ int lcnt[256];
    __shared__ int lsc[256];
    __shared__ int lcur[256];
    __shared__ float sdinv[256];
    const int tid = (int)threadIdx.x;
    const int b = (int)blockIdx.x;
    const int beg = boff[b], end = boff[b + 1];
    lcnt[tid] = 0;
    __syncthreads();
    for (int i = beg + tid; i < end; i += 256)
        atomicAdd(&lcnt[bin[i] & BMASK], 1);
    __syncthreads();
    lsc[tid] = lcnt[tid];
    __syncthreads();
    for (int off = 1; off < 256; off <<= 1) {
        int t = (tid >= off) ? lsc[tid - off] : 0;
        __syncthreads();
        lsc[tid] += t;
        __syncthreads();
    }
    int cb = lcnt[tid];
    int lb = lsc[tid] - cb;
    lcur[tid] = lb;
    float dv = cb ? rsqrtf((float)cb) : 0.0f;
    sdinv[tid] = dv;
    int node = (b << BSH) + tid;
    if (node < nN) {
        offsets[node] = beg + lb;
        dinv[node] = dv;
        rdinv[node] = cb ? sqrtf((float)cb) : 0.0f;
        if (node == nN - 1) offsets[nN] = beg + lsc[tid];
    }
    __syncthreads();
    for (int i = beg + tid; i < end; i += 256) {
        unsigned e = bin[i];
        int c = (int)(e & BMASK);
        int p = atomicAdd(&lcur[c], 1);
        row_sorted[beg + p] = (int)(e >> BSH);
    }
    // fused y0 init: 256 nodes x 8 chunks (each chunk = float4 = 8 halves)
    const int baseNode = b << BSH;
#pragma unroll
    for (int it = 0; it < 8; ++it) {
        int idx = it * 256 + tid;        // chunk within block, 0..2047
        int ln = idx >> 3;               // local node
        int node2 = baseNode + ln;
        if (node2 < nN) {
            int qc = idx & 7;
            const float* src = (node2 < nU) ? user + (size_t)node2 * DIM
                                            : item + (size_t)(node2 - nU) * DIM;
            float4 e0 = ((const float4*)src)[qc * 2];
            float4 e1 = ((const float4*)src)[qc * 2 + 1];
            float dvn = sdinv[ln];
            float4 pack;
            __half2* p = (__half2*)&pack;
            p[0] = __floats2half2_rn(dvn * e0.x, dvn * e0.y);
            p[1] = __floats2half2_rn(dvn * e0.z, dvn * e0.w);
            p[2] = __floats2half2_rn(dvn * e1.x, dvn * e1.y);
            p[3] = __floats2half2_rn(dvn * e1.z, dvn * e1.w);
            ((float4*)y0)[(size_t)baseNode * 8 + idx] = pack;
        }
    }
}

// one wave per node; 8 edge-groups x 8 lanes; each lane loads float4 (8 halves)
// -> one VMEM instruction gathers 8 rows (1KB); 2x unroll = 16 edges in flight.
// Writes only y_out = dinv^2 * sum (no out RMW).
__global__ __launch_bounds__(256) void layer_kernel(const int* __restrict__ offsets,
                                                    const int* __restrict__ row_sorted,
                                                    const float* __restrict__ dinv,
                                                    const __half* __restrict__ y_in,
                                                    __half* __restrict__ y_out,
                                                    int nN) {
    int wave = (int)((blockIdx.x * blockDim.x + threadIdx.x) >> 6);
    int lane = (int)(threadIdx.x & 63);
    if (wave >= nN) return;
    const int beg = offsets[wave];
    const int end = offsets[wave + 1];
    const int g = lane >> 3;   // edge slot 0..7
    const int q = lane & 7;    // 16B chunk of the row, 0..7
    const float4* yv = (const float4*)y_in;
    float a0 = 0, a1 = 0, a2 = 0, a3 = 0, a4 = 0, a5 = 0, a6 = 0, a7 = 0;
    const int last = end - 1;
    for (int base = beg; base < end; base += 16) {
        int e0 = base + g;
        int e1 = e0 + 8;
        int i0 = (e0 <= last) ? e0 : last;
        int i1 = (e1 <= last) ? e1 : last;
        float m0 = (e0 <= last) ? 1.0f : 0.0f;
        float m1 = (e1 <= last) ? 1.0f : 0.0f;
        int r0 = row_sorted[i0];
        int r1 = row_sorted[i1];
        float4 v0 = yv[(size_t)r0 * 8 + q];
        float4 v1 = yv[(size_t)r1 * 8 + q];
        const __half2* h0 = (const __half2*)&v0;
        const __half2* h1 = (const __half2*)&v1;
        float2 t;
        t = __half22float2(h0[0]); a0 = fmaf(m0, t.x, a0); a1 = fmaf(m0, t.y, a1);
        t = __half22float2(h0[1]); a2 = fmaf(m0, t.x, a2); a3 = fmaf(m0, t.y, a3);
        t = __half22float2(h0[2]); a4 = fmaf(m0, t.x, a4); a5 = fmaf(m0, t.y, a5);
        t = __half22float2(h0[3]); a6 = fmaf(m0, t.x, a6); a7 = fmaf(m0, t.y, a7);
        t = __half22float2(h1[0]); a0 = fmaf(m1, t.x, a0); a1 = fmaf(m1, t.y, a1);
        t = __half22float2(h1[1]); a2 = fmaf(m1, t.x, a2); a3 = fmaf(m1, t.y, a3);
        t = __half22float2(h1[2]); a4 = fmaf(m1, t.x, a4); a5 = fmaf(m1, t.y, a5);
        t = __half22float2(h1[3]); a6 = fmaf(m1, t.x, a6); a7 = fmaf(m1, t.y, a7);
    }
    // reduce across the 8 edge-groups (lane bits 3..5)
#pragma unroll
    for (int ofs = 8; ofs <= 32; ofs <<= 1) {
        a0 += __shfl_xor(a0, ofs);
        a1 += __shfl_xor(a1, ofs);
        a2 += __shfl_xor(a2, ofs);
        a3 += __shfl_xor(a3, ofs);
        a4 += __shfl_xor(a4, ofs);
        a5 += __shfl_xor(a5, ofs);
        a6 += __shfl_xor(a6, ofs);
        a7 += __shfl_xor(a7, ofs);
    }
    if (g == 0) {
        float dc = dinv[wave];
        float s = dc * dc;          // y_out = dinv * (dinv * sum)
        float4 pack;
        __half2* p = (__half2*)&pack;
        p[0] = __floats2half2_rn(s * a0, s * a1);
        p[1] = __floats2half2_rn(s * a2, s * a3);
        p[2] = __floats2half2_rn(s * a4, s * a5);
        p[3] = __floats2half2_rn(s * a6, s * a7);
        ((float4*)y_out)[(size_t)wave * 8 + q] = pack;
    }
}

// out = 0.25*(emb + rdinv*(y1+y2+y3)); one thread per 8-elem chunk
__global__ __launch_bounds__(256) void final_kernel(const float* __restrict__ user,
                                                    const float* __restrict__ item,
                                                    const float* __restrict__ rdinv,
                                                    const __half* __restrict__ y1,
                                                    const __half* __restrict__ y2,
                                                    const __half* __restrict__ y3,
                                                    float* __restrict__ out,
                                                    int nU, int nN) {
    int c = blockIdx.x * blockDim.x + threadIdx.x;
    if (c >= nN * 8) return;
    int node = c >> 3;
    int qc = c & 7;
    float rd = 0.25f * rdinv[node];
    float4 h1 = ((const float4*)y1)[c];
    float4 h2 = ((const float4*)y2)[c];
    float4 h3 = ((const float4*)y3)[c];
    const float* src = (node < nU) ? user + (size_t)node * DIM
                                   : item + (size_t)(node - nU) * DIM;
    float4 e0 = ((const float4*)src)[qc * 2];
    float4 e1 = ((const float4*)src)[qc * 2 + 1];
    const __half2* p1 = (const __half2*)&h1;
    const __half2* p2 = (const __half2*)&h2;
    const __half2* p3 = (const __half2*)&h3;
    float r[8];
#pragma unroll
    for (int j = 0; j < 4; ++j) {
        float2 u1 = __half22float2(p1[j]);
        float2 u2 = __half22float2(p2[j]);
        float2 u3 = __half22float2(p3[j]);
        r[2 * j]     = u1.x + u2.x + u3.x;
        r[2 * j + 1] = u1.y + u2.y + u3.y;
    }
    float4 o0, o1;
    o0.x = 0.25f * e0.x + rd * r[0];
    o0.y = 0.25f * e0.y + rd * r[1];
    o0.z = 0.25f * e0.z + rd * r[2];
    o0.w = 0.25f * e0.w + rd * r[3];
    o1.x = 0.25f * e1.x + rd * r[4];
    o1.y = 0.25f * e1.y + rd * r[5];
    o1.z = 0.25f * e1.z + rd * r[6];
    o1.w = 0.25f * e1.w + rd * r[7];
    ((float4*)out)[(size_t)c * 2]     = o0;
    ((float4*)out)[(size_t)c * 2 + 1] = o1;
}

// ---------------- host launcher ----------------

extern "C" void kernel_launch(void* const* d_in, const int* in_sizes, int n_in,
                              void* d_out, int out_size, void* d_ws, size_t ws_size,
                              hipStream_t stream) {
    const float* user = (const float*)d_in[0];
    const float* item = (const float*)d_in[1];
    const int*   edge = (const int*)d_in[2];

    const int nU = in_sizes[0] / DIM;
    const int nI = in_sizes[1] / DIM;
    const int nN = nU + nI;
    const int E  = in_sizes[2] / 2;
    const int total = nN * DIM;
    const int NB = (nN + 255) / 256;     // 256-node coarse buckets

    float* out = (float*)d_out;

    // workspace carve-up (256B aligned)
    char* ws = (char*)d_ws;
    size_t off = 0;
    auto take = [&](size_t bytes) -> char* {
        char* p = ws + off;
        off = (off + bytes + 255) & ~(size_t)255;
        return p;
    };
    const size_t ybytes = (size_t)total * 2;
    const size_t binbytes = (size_t)E * 4;
    int*      bcnt       = (int*)  take((size_t)NB * 4);
    int*      boff       = (int*)  take((size_t)(NB + 1) * 4);
    int*      bcur       = (int*)  take((size_t)NB * 4);
    int*      offsets    = (int*)  take((size_t)(nN + 1) * 4);
    float*    dinv       = (float*)take((size_t)nN * 4);
    float*    rdinv      = (float*)take((size_t)nN * 4);
    int*      row_sorted = (int*)  take((size_t)E * 4);
    char*     regionA    = take(binbytes > ybytes ? binbytes : ybytes);  // bin, then y1
    char*     regionB    = take(ybytes);                                 // y0, then y3
    char*     regionC    = take(ybytes);                                 // y2
    unsigned* bin = (unsigned*)regionA;
    __half*   y1  = (__half*)regionA;
    __half*   y0  = (__half*)regionB;
    __half*   y3  = (__half*)regionB;
    __half*   y2  = (__half*)regionC;
    (void)ws_size; (void)n_in; (void)out_size;

    const int B = 256;
    dim3 blk(B);

    // 1. zero bucket counts
    zero_ints<<<dim3((NB + B - 1) / B), blk, 0, stream>>>(bcnt, NB);
    // 2. bucket histogram (LDS-aggregated)
    bucket_count_kernel<<<dim3(256), dim3(1024), 0, stream>>>(edge, E, bcnt, NB);
    // 3. bucket scan
    scan_kernel<<<dim3(1), dim3(1024), 0, stream>>>(bcnt, boff, bcur, NB);
    // 4. LDS-staged scatter into bucket-sorted bin
    bin_kernel<<<dim3((E + BINC - 1) / BINC), dim3(1024), 0, stream>>>(edge, E, bcur, bin, NB);
    // 5. per-bucket counting sort -> CSR + offsets + dinv/rdinv + fused y0 init
    csr_kernel<<<dim3(NB), blk, 0, stream>>>(bin, boff, user, item, nU,
                                             offsets, dinv, rdinv, row_sorted, y0, nN);

    // 6. three propagation layers (wave per node, 8-edge-wide fp16 gathers)
    dim3 lgrid((nN + 3) / 4);   // 4 waves (nodes) per 256-thread block
    layer_kernel<<<lgrid, blk, 0, stream>>>(offsets, row_sorted, dinv, y0, y1, nN);
    layer_kernel<<<lgrid, blk, 0, stream>>>(offsets, row_sorted, dinv, y1, y2, nN);
    layer_kernel<<<lgrid, blk, 0, stream>>>(offsets, row_sorted, dinv, y2, y3, nN);

    // 7. streaming combine: out = 0.25*(emb + rdinv*(y1+y2+y3))
    final_kernel<<<dim3((nN * 8 + B - 1) / B), blk, 0, stream>>>(user, item, rdinv,
                                                                 y1, y2, y3, out, nU, nN);
}